// Round 3
// baseline (632.719 us; speedup 1.0000x reference)
//
#include <hip/hip_runtime.h>
#include <hip/hip_bf16.h>

#define N_DIM 8192
#define D_DIM 512
#define BM 128
#define BN 128
#define BK 64
#define NTILES 2080   // 64*65/2 upper-triangular 128x128 tiles
#define CHUNK_BYTES 16384   // 32 rows x 128 cols x 4B

typedef float f32x4 __attribute__((ext_vector_type(4)));
typedef short bf16x8 __attribute__((ext_vector_type(8)));
typedef unsigned int u32;

// ---------------------------------------------------------------------------
// Kernel 1: L2-normalize rows of featureMatrix -> bf16 f in workspace.
// ---------------------------------------------------------------------------
__global__ __launch_bounds__(256) void normalize_rows_k(
    const float* __restrict__ feat, __hip_bfloat16* __restrict__ fb)
{
    const int w    = threadIdx.x >> 6;
    const int lane = threadIdx.x & 63;
    const int row  = blockIdx.x * 4 + w;

    const float* src = feat + (size_t)row * D_DIM + lane * 8;
    float4 v0 = *reinterpret_cast<const float4*>(src);
    float4 v1 = *reinterpret_cast<const float4*>(src + 4);

    float ss = v0.x*v0.x + v0.y*v0.y + v0.z*v0.z + v0.w*v0.w
             + v1.x*v1.x + v1.y*v1.y + v1.z*v1.z + v1.w*v1.w;
    #pragma unroll
    for (int off = 32; off; off >>= 1) ss += __shfl_xor(ss, off);

    const float r = 1.0f / fmaxf(sqrtf(ss), 1e-12f);

    union { ushort u[8]; uint4 q; } pk;
    float vals[8] = { v0.x, v0.y, v0.z, v0.w, v1.x, v1.y, v1.z, v1.w };
    #pragma unroll
    for (int i = 0; i < 8; ++i) {
        __hip_bfloat16 b = __float2bfloat16(vals[i] * r);
        pk.u[i] = *reinterpret_cast<ushort*>(&b);
    }
    *reinterpret_cast<uint4*>(fb + (size_t)row * D_DIM + lane * 8) = pk.q;
}

// ---------------------------------------------------------------------------
// Kernel 2: symmetric fused GEMM + masked MSE, DMA-pipelined epilogue.
// Upper-triangular tiles only; off-diag blocks score both orig(br,bc) and
// orig(bc,br) against the same accumulator (C symmetric).
// Epilogue: orig streamed in 16KB chunks via global_load_lds into a 2x16KB
// LDS double-buffer, raw s_barrier + counted vmcnt (pipeline never drains),
// source addresses pre-XOR-swizzled so LDS reads are conflict-light.
// ---------------------------------------------------------------------------
__global__ __launch_bounds__(256) void fused_gemm_loss_k(
    const __hip_bfloat16* __restrict__ fb,
    const float* __restrict__ orig,
    float* __restrict__ partials)
{
    __shared__ __align__(16) __hip_bfloat16 As[BM * BK];
    __shared__ __align__(16) __hip_bfloat16 Bs[BN * BK];
    __shared__ __align__(16) float olds[2][CHUNK_BYTES / 4];
    __shared__ float red[8];

    // map bid -> upper-triangular (br, bc)
    int b = blockIdx.x, br = 0;
    while (b >= 64 - br) { b -= 64 - br; ++br; }
    const int bc  = br + b;
    const int tr0 = br * BM;
    const int tc0 = bc * BN;

    const int tid  = threadIdx.x;
    const int w    = tid >> 6;
    const int lane = tid & 63;
    const int wr   = w >> 1;        // 0..1
    const int wc   = w & 1;         // 0..1
    const int fr   = lane & 15;
    const int rsub = (lane >> 4) * 4;

    // ---- orig-chunk DMA issue (pre-swizzled source, linear LDS dest) ----
    // chunk cc: 0..3 normal (rows tr0+cc*32, cols tc0), 4..7 mirror
    // (rows tc0+(cc-4)*32, cols tr0). 16KB = 32 rows x 512B.
    auto issue_chunk = [&](int cc, int half) {
        const int mir   = cc >> 2;
        const int cr    = cc & 3;
        const int rbase = (mir ? tc0 : tr0) + cr * 32;
        const int cbase = (mir ? tr0 : tc0);
        #pragma unroll
        for (int t = 0; t < 4; ++t) {
            const int xb   = (w * 4 + t) * 1024;          // wave-uniform LDS base
            const int x    = xb + lane * 16;              // this lane's byte
            const int rowc = x >> 9;                      // 0..31
            const int within = (x & 511) ^ ((rowc & 7) << 4);
            const float* src = orig + (size_t)(rbase + rowc) * N_DIM
                                    + cbase + (within >> 2);
            __builtin_amdgcn_global_load_lds(
                (const __attribute__((address_space(1))) u32*)src,
                (__attribute__((address_space(3))) u32*)
                    ((char*)&olds[half][0] + xb),
                16, 0, 0);
        }
    };

    // prefetch first two orig chunks; latency hides under the K-loop
    issue_chunk(0, 0);
    issue_chunk(1, 1);

    f32x4 acc[4][4] = {};

    // fb staging geometry: 16 chunks of 1 KiB
    const int srow = lane >> 3;
    const int scol = (lane & 7) * 8;

    for (int k0 = 0; k0 < D_DIM; k0 += BK) {
        #pragma unroll
        for (int t = 0; t < 4; ++t) {
            const int c = w * 4 + t;
            const int rowA = tr0 + c * 8 + srow;
            const int rowB = tc0 + c * 8 + srow;
            const __hip_bfloat16* gA = fb + (size_t)rowA * D_DIM + k0 + scol;
            const __hip_bfloat16* gB = fb + (size_t)rowB * D_DIM + k0 + scol;
            __builtin_amdgcn_global_load_lds(
                (const __attribute__((address_space(1))) u32*)gA,
                (__attribute__((address_space(3))) u32*)(As + c * 512),
                16, 0, 0);
            __builtin_amdgcn_global_load_lds(
                (const __attribute__((address_space(1))) u32*)gB,
                (__attribute__((address_space(3))) u32*)(Bs + c * 512),
                16, 0, 0);
        }
        __syncthreads();

        const int krow = lane >> 4;
        #pragma unroll
        for (int kk = 0; kk < BK; kk += 32) {
            bf16x8 af[4], bfr[4];
            #pragma unroll
            for (int fm = 0; fm < 4; ++fm)
                af[fm] = *reinterpret_cast<const bf16x8*>(
                    As + (wr * 64 + fm * 16 + fr) * BK + kk + krow * 8);
            #pragma unroll
            for (int fn = 0; fn < 4; ++fn)
                bfr[fn] = *reinterpret_cast<const bf16x8*>(
                    Bs + (wc * 64 + fn * 16 + fr) * BK + kk + krow * 8);
            #pragma unroll
            for (int fm = 0; fm < 4; ++fm)
                #pragma unroll
                for (int fn = 0; fn < 4; ++fn)
                    acc[fm][fn] = __builtin_amdgcn_mfma_f32_16x16x32_bf16(
                        af[fm], bfr[fn], acc[fm][fn], 0, 0, 0);
        }
        __syncthreads();
    }

    // ---- DMA-pipelined masked-MSE epilogue ----
    float lsum = 0.0f, lcnt = 0.0f;
    const int nch = (br == bc) ? 4 : 8;

    for (int c = 0; c < nch; ++c) {
        // wait for chunk c (per-wave), then sync all waves
        if (c == nch - 1) asm volatile("s_waitcnt vmcnt(0)" ::: "memory");
        else              asm volatile("s_waitcnt vmcnt(4)" ::: "memory");
        __builtin_amdgcn_s_barrier();
        __builtin_amdgcn_sched_barrier(0);

        const char* L = (const char*)&olds[c & 1][0];
        if (c < 4) {
            // normal chunk: tile rows [c*32, c*32+32); waves wr == c>>1
            if (wr == (c >> 1)) {
                #pragma unroll
                for (int fmi = 0; fmi < 2; ++fmi) {
                    const int fm = (c & 1) * 2 + fmi;
                    #pragma unroll
                    for (int v = 0; v < 4; ++v) {
                        const int rowc = fmi * 16 + rsub + v;
                        const int sw   = (rowc & 7) << 4;
                        #pragma unroll
                        for (int fn = 0; fn < 4; ++fn) {
                            const int colb = (wc * 64 + fn * 16 + fr) * 4;
                            const float o = *(const float*)(L + rowc * 512 + (colb ^ sw));
                            if (o != 0.0f) {
                                const float d = o - acc[fm][fn][v];
                                lsum += d * d; lcnt += 1.0f;
                            }
                        }
                    }
                }
            }
        } else {
            // mirror chunk: orig rows (=C cols) [cr*32, +32); waves wc == cr>>1
            const int cr = c - 4;
            if (wc == (cr >> 1)) {
                #pragma unroll
                for (int fni = 0; fni < 2; ++fni) {
                    const int fn   = (cr & 1) * 2 + fni;
                    const int rowc = fni * 16 + fr;
                    const int sw   = (rowc & 7) << 4;
                    #pragma unroll
                    for (int fm = 0; fm < 4; ++fm) {
                        const int colb0 = (wr * 64 + fm * 16 + rsub) * 4;
                        const float4 o4 = *(const float4*)(L + rowc * 512 + (colb0 ^ sw));
                        const float ov[4] = { o4.x, o4.y, o4.z, o4.w };
                        #pragma unroll
                        for (int v = 0; v < 4; ++v) {
                            if (ov[v] != 0.0f) {
                                const float d = ov[v] - acc[fm][fn][v];
                                lsum += d * d; lcnt += 1.0f;
                            }
                        }
                    }
                }
            }
        }

        // all waves done reading buf[c&1] before re-staging into it
        __builtin_amdgcn_s_barrier();
        __builtin_amdgcn_sched_barrier(0);
        if (c + 2 < nch) issue_chunk(c + 2, c & 1);
    }

    #pragma unroll
    for (int off = 32; off; off >>= 1) {
        lsum += __shfl_xor(lsum, off);
        lcnt += __shfl_xor(lcnt, off);
    }
    if (lane == 0) { red[w * 2] = lsum; red[w * 2 + 1] = lcnt; }
    __syncthreads();
    if (tid == 0) {
        float s = 0.0f, cnt = 0.0f;
        #pragma unroll
        for (int i = 0; i < 4; ++i) { s += red[i * 2]; cnt += red[i * 2 + 1]; }
        partials[(size_t)blockIdx.x * 2]     = s;
        partials[(size_t)blockIdx.x * 2 + 1] = cnt;
    }
}

// ---------------------------------------------------------------------------
// Kernel 3: deterministic reduce of per-block partials -> out[0] = sum/count
// ---------------------------------------------------------------------------
__global__ __launch_bounds__(256) void final_reduce_k(
    const float* __restrict__ partials, float* __restrict__ out, int nb)
{
    __shared__ float rs[4], rc[4];
    float s = 0.0f, c = 0.0f;
    for (int i = threadIdx.x; i < nb; i += 256) {
        s += partials[(size_t)i * 2];
        c += partials[(size_t)i * 2 + 1];
    }
    #pragma unroll
    for (int off = 32; off; off >>= 1) {
        s += __shfl_xor(s, off);
        c += __shfl_xor(c, off);
    }
    const int w = threadIdx.x >> 6, lane = threadIdx.x & 63;
    if (lane == 0) { rs[w] = s; rc[w] = c; }
    __syncthreads();
    if (threadIdx.x == 0) {
        const float S = rs[0] + rs[1] + rs[2] + rs[3];
        const float C = rc[0] + rc[1] + rc[2] + rc[3];
        out[0] = S / C;
    }
}

// ---------------------------------------------------------------------------
extern "C" void kernel_launch(void* const* d_in, const int* in_sizes, int n_in,
                              void* d_out, int out_size, void* d_ws, size_t ws_size,
                              hipStream_t stream)
{
    const float* orig = (const float*)d_in[0];   // originalMatrix [N,N]
    const float* feat = (const float*)d_in[1];   // featureMatrix  [N,D]
    float* out = (float*)d_out;

    __hip_bfloat16* fb = (__hip_bfloat16*)d_ws;                       // 8 MiB
    float* partials = (float*)((char*)d_ws + (size_t)N_DIM * D_DIM * 2);

    normalize_rows_k<<<N_DIM / 4, 256, 0, stream>>>(feat, fb);
    fused_gemm_loss_k<<<NTILES, 256, 0, stream>>>(fb, orig, partials);
    final_reduce_k<<<1, 256, 0, stream>>>(partials, out, NTILES);
}

// Round 4
// 117.744 us; speedup vs baseline: 5.3737x; 5.3737x over previous
//
#include <hip/hip_runtime.h>
#include <hip/hip_bf16.h>

#define N_DIM 8192
#define D_DIM 512
#define BM 128
#define BN 128
#define BK 64
#define NTILES 2080   // 64*65/2 upper-triangular 128x128 tiles
#define CHUNK_BYTES 16384   // 32 rows x 128 cols x 4B

typedef float f32x4 __attribute__((ext_vector_type(4)));
typedef short bf16x8 __attribute__((ext_vector_type(8)));
typedef unsigned int u32;

template<int V> struct IC { static constexpr int value = V; };

// ---------------------------------------------------------------------------
// Kernel 1: L2-normalize rows of featureMatrix -> bf16 f in workspace.
// ---------------------------------------------------------------------------
__global__ __launch_bounds__(256) void normalize_rows_k(
    const float* __restrict__ feat, __hip_bfloat16* __restrict__ fb)
{
    const int w    = threadIdx.x >> 6;
    const int lane = threadIdx.x & 63;
    const int row  = blockIdx.x * 4 + w;

    const float* src = feat + (size_t)row * D_DIM + lane * 8;
    float4 v0 = *reinterpret_cast<const float4*>(src);
    float4 v1 = *reinterpret_cast<const float4*>(src + 4);

    float ss = v0.x*v0.x + v0.y*v0.y + v0.z*v0.z + v0.w*v0.w
             + v1.x*v1.x + v1.y*v1.y + v1.z*v1.z + v1.w*v1.w;
    #pragma unroll
    for (int off = 32; off; off >>= 1) ss += __shfl_xor(ss, off);

    const float r = 1.0f / fmaxf(sqrtf(ss), 1e-12f);

    union { ushort u[8]; uint4 q; } pk;
    float vals[8] = { v0.x, v0.y, v0.z, v0.w, v1.x, v1.y, v1.z, v1.w };
    #pragma unroll
    for (int i = 0; i < 8; ++i) {
        __hip_bfloat16 b = __float2bfloat16(vals[i] * r);
        pk.u[i] = *reinterpret_cast<ushort*>(&b);
    }
    *reinterpret_cast<uint4*>(fb + (size_t)row * D_DIM + lane * 8) = pk.q;
}

// ---------------------------------------------------------------------------
// Kernel 2: symmetric fused GEMM + masked MSE, DMA-pipelined epilogue.
// Upper-triangular tiles only; off-diag blocks score both orig(br,bc) and
// orig(bc,br) against the same accumulator (C symmetric).
//
// Epilogue chunk layout (all 4 waves active per chunk; acc indices are
// compile-time — chunk c<4 <-> fm=c, chunk c>=4 <-> fn=c-4):
//   normal chunk c : orig rows {tr0+c*16..+16} u {tr0+64+c*16..+16}, 128 cols
//   mirror chunk c : orig rows {tc0+(c-4)*16..+16} u {tc0+64+..}, 128 cols
// Staged 16KB/chunk via global_load_lds (pre-XOR-swizzled source, linear LDS
// dest), 2x16KB double buffer, counted vmcnt + raw s_barrier pipeline.
// ---------------------------------------------------------------------------
__global__ __launch_bounds__(256) void fused_gemm_loss_k(
    const __hip_bfloat16* __restrict__ fb,
    const float* __restrict__ orig,
    float* __restrict__ partials)
{
    __shared__ __align__(16) __hip_bfloat16 As[BM * BK];
    __shared__ __align__(16) __hip_bfloat16 Bs[BN * BK];
    __shared__ __align__(16) float olds[2][CHUNK_BYTES / 4];
    __shared__ float red[8];

    // map bid -> upper-triangular (br, bc)
    int b = blockIdx.x, br = 0;
    while (b >= 64 - br) { b -= 64 - br; ++br; }
    const int bc  = br + b;
    const int tr0 = br * BM;
    const int tc0 = bc * BN;

    const int tid  = threadIdx.x;
    const int w    = tid >> 6;
    const int lane = tid & 63;
    const int wr   = w >> 1;        // 0..1
    const int wc   = w & 1;         // 0..1
    const int fr   = lane & 15;
    const int rsub = (lane >> 4) * 4;

    // ---- orig-chunk DMA issue (pre-swizzled source, linear LDS dest) ----
    auto issue_chunk = [&](int cc, int half) {
        const int mir = cc >> 2;
        const int rb  = (mir ? tc0 : tr0) + (cc & 3) * 16;
        const int cb  = (mir ? tr0 : tc0);
        #pragma unroll
        for (int t = 0; t < 4; ++t) {
            const int xb   = (w * 4 + t) * 1024;          // wave-uniform LDS base
            const int x    = xb + lane * 16;              // this lane's byte
            const int rowc = x >> 9;                      // 0..31
            const int grow = rb + ((rowc >> 4) * 64) + (rowc & 15);
            const int within = (x & 511) ^ ((rowc & 7) << 4);
            const float* src = orig + (size_t)grow * N_DIM + cb + (within >> 2);
            __builtin_amdgcn_global_load_lds(
                (const __attribute__((address_space(1))) u32*)src,
                (__attribute__((address_space(3))) u32*)
                    ((char*)&olds[half][0] + xb),
                16, 0, 0);
        }
    };

    // prefetch first two orig chunks; latency hides under the K-loop
    issue_chunk(0, 0);
    issue_chunk(1, 1);

    f32x4 acc[4][4] = {};

    // fb staging geometry: 16 chunks of 1 KiB
    const int srow = lane >> 3;
    const int scol = (lane & 7) * 8;

    for (int k0 = 0; k0 < D_DIM; k0 += BK) {
        #pragma unroll
        for (int t = 0; t < 4; ++t) {
            const int c = w * 4 + t;
            const int rowA = tr0 + c * 8 + srow;
            const int rowB = tc0 + c * 8 + srow;
            const __hip_bfloat16* gA = fb + (size_t)rowA * D_DIM + k0 + scol;
            const __hip_bfloat16* gB = fb + (size_t)rowB * D_DIM + k0 + scol;
            __builtin_amdgcn_global_load_lds(
                (const __attribute__((address_space(1))) u32*)gA,
                (__attribute__((address_space(3))) u32*)(As + c * 512),
                16, 0, 0);
            __builtin_amdgcn_global_load_lds(
                (const __attribute__((address_space(1))) u32*)gB,
                (__attribute__((address_space(3))) u32*)(Bs + c * 512),
                16, 0, 0);
        }
        __syncthreads();

        const int krow = lane >> 4;
        #pragma unroll
        for (int kk = 0; kk < BK; kk += 32) {
            bf16x8 af[4], bfr[4];
            #pragma unroll
            for (int fm = 0; fm < 4; ++fm)
                af[fm] = *reinterpret_cast<const bf16x8*>(
                    As + (wr * 64 + fm * 16 + fr) * BK + kk + krow * 8);
            #pragma unroll
            for (int fn = 0; fn < 4; ++fn)
                bfr[fn] = *reinterpret_cast<const bf16x8*>(
                    Bs + (wc * 64 + fn * 16 + fr) * BK + kk + krow * 8);
            #pragma unroll
            for (int fm = 0; fm < 4; ++fm)
                #pragma unroll
                for (int fn = 0; fn < 4; ++fn)
                    acc[fm][fn] = __builtin_amdgcn_mfma_f32_16x16x32_bf16(
                        af[fm], bfr[fn], acc[fm][fn], 0, 0, 0);
        }
        __syncthreads();
    }

    // ---- DMA-pipelined masked-MSE epilogue (fully unrolled, acc in regs) ----
    float lsum = 0.0f, lcnt = 0.0f;

    auto epi = [&](auto nch_c) {
        constexpr int NCH = decltype(nch_c)::value;
        #pragma unroll
        for (int c = 0; c < NCH; ++c) {
            // chunks 0/1 were drained by the K-loop's __syncthreads
            if (c >= 2) {
                if (c == NCH - 1) asm volatile("s_waitcnt vmcnt(0)" ::: "memory");
                else              asm volatile("s_waitcnt vmcnt(4)" ::: "memory");
                __builtin_amdgcn_s_barrier();
                __builtin_amdgcn_sched_barrier(0);
            }
            const char* L = (const char*)&olds[c & 1][0];
            if (c < 4) {
                // normal chunk: fm = c (compile-time after unroll)
                #pragma unroll
                for (int v = 0; v < 4; ++v) {
                    const int rc = wr * 16 + rsub + v;
                    const int sw = (rc & 7) << 4;
                    #pragma unroll
                    for (int fn = 0; fn < 4; ++fn) {
                        const int colb = (wc * 64 + fn * 16 + fr) * 4;
                        const float o = *(const float*)(L + rc * 512 + (colb ^ sw));
                        if (o != 0.0f) {
                            const float d = o - acc[c][fn][v];
                            lsum += d * d; lcnt += 1.0f;
                        }
                    }
                }
            } else {
                // mirror chunk: fn = c-4 (compile-time after unroll)
                const int rc = wc * 16 + fr;
                const int sw = (rc & 7) << 4;
                #pragma unroll
                for (int fm = 0; fm < 4; ++fm) {
                    const int colb = (wr * 64 + fm * 16 + rsub) * 4;
                    const float4 o4 = *(const float4*)(L + rc * 512 + (colb ^ sw));
                    const float ov[4] = { o4.x, o4.y, o4.z, o4.w };
                    #pragma unroll
                    for (int v = 0; v < 4; ++v) {
                        if (ov[v] != 0.0f) {
                            const float d = ov[v] - acc[fm][c - 4][v];
                            lsum += d * d; lcnt += 1.0f;
                        }
                    }
                }
            }
            if (c + 2 < NCH) {
                // all waves done reading buf[c&1] before re-staging into it
                __builtin_amdgcn_s_barrier();
                __builtin_amdgcn_sched_barrier(0);
                issue_chunk(c + 2, c & 1);
            }
        }
    };

    if (br == bc) epi(IC<4>{});
    else          epi(IC<8>{});

    #pragma unroll
    for (int off = 32; off; off >>= 1) {
        lsum += __shfl_xor(lsum, off);
        lcnt += __shfl_xor(lcnt, off);
    }
    if (lane == 0) { red[w * 2] = lsum; red[w * 2 + 1] = lcnt; }
    __syncthreads();
    if (tid == 0) {
        float s = 0.0f, cnt = 0.0f;
        #pragma unroll
        for (int i = 0; i < 4; ++i) { s += red[i * 2]; cnt += red[i * 2 + 1]; }
        partials[(size_t)blockIdx.x * 2]     = s;
        partials[(size_t)blockIdx.x * 2 + 1] = cnt;
    }
}

// ---------------------------------------------------------------------------
// Kernel 3: deterministic reduce of per-block partials -> out[0] = sum/count
// ---------------------------------------------------------------------------
__global__ __launch_bounds__(256) void final_reduce_k(
    const float* __restrict__ partials, float* __restrict__ out, int nb)
{
    __shared__ float rs[4], rc[4];
    float s = 0.0f, c = 0.0f;
    for (int i = threadIdx.x; i < nb; i += 256) {
        s += partials[(size_t)i * 2];
        c += partials[(size_t)i * 2 + 1];
    }
    #pragma unroll
    for (int off = 32; off; off >>= 1) {
        s += __shfl_xor(s, off);
        c += __shfl_xor(c, off);
    }
    const int w = threadIdx.x >> 6, lane = threadIdx.x & 63;
    if (lane == 0) { rs[w] = s; rc[w] = c; }
    __syncthreads();
    if (threadIdx.x == 0) {
        const float S = rs[0] + rs[1] + rs[2] + rs[3];
        const float C = rc[0] + rc[1] + rc[2] + rc[3];
        out[0] = S / C;
    }
}

// ---------------------------------------------------------------------------
extern "C" void kernel_launch(void* const* d_in, const int* in_sizes, int n_in,
                              void* d_out, int out_size, void* d_ws, size_t ws_size,
                              hipStream_t stream)
{
    const float* orig = (const float*)d_in[0];   // originalMatrix [N,N]
    const float* feat = (const float*)d_in[1];   // featureMatrix  [N,D]
    float* out = (float*)d_out;

    __hip_bfloat16* fb = (__hip_bfloat16*)d_ws;                       // 8 MiB
    float* partials = (float*)((char*)d_ws + (size_t)N_DIM * D_DIM * 2);

    normalize_rows_k<<<N_DIM / 4, 256, 0, stream>>>(feat, fb);
    fused_gemm_loss_k<<<NTILES, 256, 0, stream>>>(fb, orig, partials);
    final_reduce_k<<<1, 256, 0, stream>>>(partials, out, NTILES);
}

// Round 5
// 88.662 us; speedup vs baseline: 7.1363x; 1.3280x over previous
//
#include <hip/hip_runtime.h>
#include <hip/hip_bf16.h>

#define N_DIM 8192
#define D_DIM 512
#define BM 128
#define BN 128
#define BK 64
#define NTILES 2080   // 64*65/2 upper-triangular 128x128 tiles

typedef float f32x4 __attribute__((ext_vector_type(4)));
typedef short bf16x8 __attribute__((ext_vector_type(8)));
typedef unsigned int u32;

// ---------------------------------------------------------------------------
// Kernel 1: L2-normalize rows of featureMatrix -> bf16 f in workspace.
// ---------------------------------------------------------------------------
__global__ __launch_bounds__(256) void normalize_rows_k(
    const float* __restrict__ feat, __hip_bfloat16* __restrict__ fb)
{
    const int w    = threadIdx.x >> 6;
    const int lane = threadIdx.x & 63;
    const int row  = blockIdx.x * 4 + w;

    const float* src = feat + (size_t)row * D_DIM + lane * 8;
    float4 v0 = *reinterpret_cast<const float4*>(src);
    float4 v1 = *reinterpret_cast<const float4*>(src + 4);

    float ss = v0.x*v0.x + v0.y*v0.y + v0.z*v0.z + v0.w*v0.w
             + v1.x*v1.x + v1.y*v1.y + v1.z*v1.z + v1.w*v1.w;
    #pragma unroll
    for (int off = 32; off; off >>= 1) ss += __shfl_xor(ss, off);

    const float r = 1.0f / fmaxf(sqrtf(ss), 1e-12f);

    union { ushort u[8]; uint4 q; } pk;
    float vals[8] = { v0.x, v0.y, v0.z, v0.w, v1.x, v1.y, v1.z, v1.w };
    #pragma unroll
    for (int i = 0; i < 8; ++i) {
        __hip_bfloat16 b = __float2bfloat16(vals[i] * r);
        pk.u[i] = *reinterpret_cast<ushort*>(&b);
    }
    *reinterpret_cast<uint4*>(fb + (size_t)row * D_DIM + lane * 8) = pk.q;
}

// ---------------------------------------------------------------------------
// Kernel 2: symmetric fused GEMM + masked MSE.
// Upper-triangular tiles only; off-diag blocks score both orig(br,bc) and
// orig(bc,br) [mirror read, contiguous float4] against the same accumulator.
//
// T2 fix: fb tiles are XOR-swizzled (byte offset ^= (row&7)<<4) to kill the
// 16-way bank conflict of 128B-stride ds_read_b128.  gload_lds writes
// linearly, so the SOURCE address carries the inverse permutation and the
// ds_read applies the same involution (both-sides-or-neither, rule #21).
// LDS is just As+Bs (32.1 KB) -> 3-4 blocks/CU for TLP latency hiding.
// ---------------------------------------------------------------------------
__global__ __launch_bounds__(256, 3) void fused_gemm_loss_k(
    const __hip_bfloat16* __restrict__ fb,
    const float* __restrict__ orig,
    float* __restrict__ partials)
{
    __shared__ __align__(16) __hip_bfloat16 As[BM * BK];
    __shared__ __align__(16) __hip_bfloat16 Bs[BN * BK];
    __shared__ float red[8];

    // map bid -> upper-triangular (br, bc)
    int b = blockIdx.x, br = 0;
    while (b >= 64 - br) { b -= 64 - br; ++br; }
    const int bc  = br + b;
    const int tr0 = br * BM;
    const int tc0 = bc * BN;

    const int tid  = threadIdx.x;
    const int w    = tid >> 6;
    const int lane = tid & 63;
    const int wr   = w >> 1;        // 0..1
    const int wc   = w & 1;         // 0..1
    const int fr   = lane & 15;
    const int rsub = (lane >> 4) * 4;

    f32x4 acc[4][4] = {};

    // fb staging: 16 chunks of 1 KiB; chunk c covers LDS rows c*8..c*8+8.
    // Lane dest byte (linear) = c*1024 + lane*16 -> row c*8+(lane>>3),
    // within-row bits4-6 = lane&7.  Source col pre-swizzled: ^ (lane>>3).
    const int srow  = lane >> 3;                         // row within chunk
    const int scols = (((lane & 7) ^ (lane >> 3)) * 8);  // swizzled col elem

    for (int k0 = 0; k0 < D_DIM; k0 += BK) {
        #pragma unroll
        for (int t = 0; t < 4; ++t) {
            const int c = w * 4 + t;
            const int rowA = tr0 + c * 8 + srow;
            const int rowB = tc0 + c * 8 + srow;
            const __hip_bfloat16* gA = fb + (size_t)rowA * D_DIM + k0 + scols;
            const __hip_bfloat16* gB = fb + (size_t)rowB * D_DIM + k0 + scols;
            __builtin_amdgcn_global_load_lds(
                (const __attribute__((address_space(1))) u32*)gA,
                (__attribute__((address_space(3))) u32*)(As + c * 512),
                16, 0, 0);
            __builtin_amdgcn_global_load_lds(
                (const __attribute__((address_space(1))) u32*)gB,
                (__attribute__((address_space(3))) u32*)(Bs + c * 512),
                16, 0, 0);
        }
        __syncthreads();

        const int krow = lane >> 4;
        const int sw   = (fr & 7) << 4;                  // read-side swizzle
        #pragma unroll
        for (int kk = 0; kk < BK; kk += 32) {
            bf16x8 af[4], bfr[4];
            #pragma unroll
            for (int fm = 0; fm < 4; ++fm) {
                const int r = wr * 64 + fm * 16 + fr;
                af[fm] = *reinterpret_cast<const bf16x8*>(
                    (const char*)As + r * 128 + (((kk << 1) + (krow << 4)) ^ sw));
            }
            #pragma unroll
            for (int fn = 0; fn < 4; ++fn) {
                const int r = wc * 64 + fn * 16 + fr;
                bfr[fn] = *reinterpret_cast<const bf16x8*>(
                    (const char*)Bs + r * 128 + (((kk << 1) + (krow << 4)) ^ sw));
            }
            #pragma unroll
            for (int fm = 0; fm < 4; ++fm)
                #pragma unroll
                for (int fn = 0; fn < 4; ++fn)
                    acc[fm][fn] = __builtin_amdgcn_mfma_f32_16x16x32_bf16(
                        af[fm], bfr[fn], acc[fm][fn], 0, 0, 0);
        }
        __syncthreads();
    }

    // ---- fused masked-MSE epilogue (direct global reads, TLP-hidden) ----
    // C/D layout: col = lane&15, row = (lane>>4)*4 + v
    float lsum = 0.0f, lcnt = 0.0f;

    // normal tile (br, bc): per-row scalar reads (16-lane coalesced)
    #pragma unroll
    for (int fm = 0; fm < 4; ++fm) {
        #pragma unroll
        for (int v = 0; v < 4; ++v) {
            const int row = tr0 + wr * 64 + fm * 16 + rsub + v;
            const float* orow = orig + (size_t)row * N_DIM + tc0 + wc * 64;
            #pragma unroll
            for (int fn = 0; fn < 4; ++fn) {
                const float o = orow[fn * 16 + fr];
                if (o != 0.0f) {
                    const float d = o - acc[fm][fn][v];
                    lsum += d * d;
                    lcnt += 1.0f;
                }
            }
        }
    }

    // mirror tile (bc, br): orig[col][row..row+3] contiguous -> float4
    if (br != bc) {
        #pragma unroll
        for (int fm = 0; fm < 4; ++fm) {
            const int rbase = tr0 + wr * 64 + fm * 16 + rsub;
            #pragma unroll
            for (int fn = 0; fn < 4; ++fn) {
                const int col = tc0 + wc * 64 + fn * 16 + fr;
                const float4 o4 = *reinterpret_cast<const float4*>(
                    orig + (size_t)col * N_DIM + rbase);
                const float ov[4] = { o4.x, o4.y, o4.z, o4.w };
                #pragma unroll
                for (int v = 0; v < 4; ++v) {
                    if (ov[v] != 0.0f) {
                        const float d = ov[v] - acc[fm][fn][v];
                        lsum += d * d;
                        lcnt += 1.0f;
                    }
                }
            }
        }
    }

    #pragma unroll
    for (int off = 32; off; off >>= 1) {
        lsum += __shfl_xor(lsum, off);
        lcnt += __shfl_xor(lcnt, off);
    }
    if (lane == 0) { red[w * 2] = lsum; red[w * 2 + 1] = lcnt; }
    __syncthreads();
    if (tid == 0) {
        float s = 0.0f, c = 0.0f;
        #pragma unroll
        for (int i = 0; i < 4; ++i) { s += red[i * 2]; c += red[i * 2 + 1]; }
        partials[(size_t)blockIdx.x * 2]     = s;
        partials[(size_t)blockIdx.x * 2 + 1] = c;
    }
}

// ---------------------------------------------------------------------------
// Kernel 3: deterministic reduce of per-block partials -> out[0] = sum/count
// ---------------------------------------------------------------------------
__global__ __launch_bounds__(256) void final_reduce_k(
    const float* __restrict__ partials, float* __restrict__ out, int nb)
{
    __shared__ float rs[4], rc[4];
    float s = 0.0f, c = 0.0f;
    for (int i = threadIdx.x; i < nb; i += 256) {
        s += partials[(size_t)i * 2];
        c += partials[(size_t)i * 2 + 1];
    }
    #pragma unroll
    for (int off = 32; off; off >>= 1) {
        s += __shfl_xor(s, off);
        c += __shfl_xor(c, off);
    }
    const int w = threadIdx.x >> 6, lane = threadIdx.x & 63;
    if (lane == 0) { rs[w] = s; rc[w] = c; }
    __syncthreads();
    if (threadIdx.x == 0) {
        const float S = rs[0] + rs[1] + rs[2] + rs[3];
        const float C = rc[0] + rc[1] + rc[2] + rc[3];
        out[0] = S / C;
    }
}

// ---------------------------------------------------------------------------
extern "C" void kernel_launch(void* const* d_in, const int* in_sizes, int n_in,
                              void* d_out, int out_size, void* d_ws, size_t ws_size,
                              hipStream_t stream)
{
    const float* orig = (const float*)d_in[0];   // originalMatrix [N,N]
    const float* feat = (const float*)d_in[1];   // featureMatrix  [N,D]
    float* out = (float*)d_out;

    __hip_bfloat16* fb = (__hip_bfloat16*)d_ws;                       // 8 MiB
    float* partials = (float*)((char*)d_ws + (size_t)N_DIM * D_DIM * 2);

    normalize_rows_k<<<N_DIM / 4, 256, 0, stream>>>(feat, fb);
    fused_gemm_loss_k<<<NTILES, 256, 0, stream>>>(fb, orig, partials);
    final_reduce_k<<<1, 256, 0, stream>>>(partials, out, NTILES);
}